// Round 1
// baseline (138.946 us; speedup 1.0000x reference)
//
#include <hip/hip_runtime.h>
#include <cstddef>

#define BB 64
#define MM 5
#define NN 1000
#define DD 128
#define HH 8
#define KSZ 16
#define NC 4
#define CHUNK 250
#define INV_SQRT_D 0.08838834764831845f

__device__ __forceinline__ float tanh_fast(float x) {
  float e = __expf(2.f * x);
  return 1.f - 2.f / (e + 1.f);   // safe at +/-inf
}

// One block per (b,h): compat -> joint softmax over (m,n) -> heads (+gVd corr via AF)
__global__ __launch_bounds__(256) void k2_attn(
    const float* __restrict__ fc, const float* __restrict__ pne,
    const float* __restrict__ vdf, const float* __restrict__ ndf,
    const float* __restrict__ gV, const float* __restrict__ gK,
    const int* __restrict__ mask, const float* __restrict__ wpcv,
    const float* __restrict__ wpns, float* __restrict__ conc)
{
  const int b = blockIdx.x >> 3;
  const int h = blockIdx.x & 7;
  const int t = threadIdx.x;

  __shared__ __align__(16) float qs[MM][KSZ];
  __shared__ __align__(16) float qw[MM][8];
  __shared__ float comp[MM][NN];
  __shared__ float red[4][MM][KSZ];
  __shared__ float redaf[4][MM][8];
  __shared__ float afs[MM][8];
  __shared__ float gredm[4];
  __shared__ float greds[4];

  // ---- Q for this head: query[b,m,h*16+k] = fc + [pne|vdf] @ W_pcv.T
  if (t < MM * KSZ) {
    const int m = t >> 4, k = t & 15;
    const int d = h * KSZ + k;
    const float* row = wpcv + d * 131;
    const float* p = pne + (b * MM + m) * DD;
    float acc = fc[b * DD + d];
#pragma unroll 8
    for (int j = 0; j < DD; ++j) acc = fmaf(p[j], row[j], acc);
    const float* v = vdf + (b * MM + m) * 3;
    acc += v[0] * row[128] + v[1] * row[129] + v[2] * row[130];
    qs[m][k] = acc;
  }
  __syncthreads();
  // ---- QW[m][f] = sum_k Q[m,k] * W_pns[128 + h*16 + k, f]
  if (t < MM * 8) {
    const int m = t >> 3, f = t & 7;
    float acc = 0.f;
#pragma unroll
    for (int k = 0; k < KSZ; ++k)
      acc = fmaf(qs[m][k], wpns[(DD + h * KSZ + k) * 8 + f], acc);
    qw[m][f] = acc;
  }
  __syncthreads();

  // ---- compat[m][n] = 0.25*(Q.K_static + ndf.QW) + mask_log
  float lmax = -3e38f;
  const float* gkb = gK + (size_t)(h * BB + b) * (NN * KSZ);
  for (int n = t; n < NN; n += 256) {
    const float4* Kp = (const float4*)(gkb + n * KSZ);
    const float4 k0 = Kp[0], k1 = Kp[1], k2 = Kp[2], k3 = Kp[3];
#pragma unroll
    for (int m = 0; m < MM; ++m) {
      const float4* fp = (const float4*)(ndf + ((size_t)(b * MM + m) * NN + n) * 8);
      const float4 f0 = fp[0], f1 = fp[1];
      const float4* qm = (const float4*)qs[m];
      const float4 q0 = qm[0], q1 = qm[1], q2 = qm[2], q3 = qm[3];
      const float4* wm = (const float4*)qw[m];
      const float4 w0 = wm[0], w1 = wm[1];
      float dot = k0.x * q0.x + k0.y * q0.y + k0.z * q0.z + k0.w * q0.w;
      dot += k1.x * q1.x + k1.y * q1.y + k1.z * q1.z + k1.w * q1.w;
      dot += k2.x * q2.x + k2.y * q2.y + k2.z * q2.z + k2.w * q2.w;
      dot += k3.x * q3.x + k3.y * q3.y + k3.z * q3.z + k3.w * q3.w;
      dot += f0.x * w0.x + f0.y * w0.y + f0.z * w0.z + f0.w * w0.w;
      dot += f1.x * w1.x + f1.y * w1.y + f1.z * w1.z + f1.w * w1.w;
      const int mk = mask[(b * MM + m) * NN + n];
      const float cval = 0.25f * dot + (mk ? 0.f : -1e30f);
      comp[m][n] = cval;
      lmax = fmaxf(lmax, cval);
    }
  }
#pragma unroll
  for (int off = 32; off > 0; off >>= 1)
    lmax = fmaxf(lmax, __shfl_xor(lmax, off));
  if ((t & 63) == 0) gredm[t >> 6] = lmax;
  __syncthreads();
  const float gmax = fmaxf(fmaxf(gredm[0], gredm[1]), fmaxf(gredm[2], gredm[3]));

  float lsum = 0.f;
  for (int n = t; n < NN; n += 256) {
#pragma unroll
    for (int m = 0; m < MM; ++m) {
      const float e = __expf(comp[m][n] - gmax);
      comp[m][n] = e;
      lsum += e;
    }
  }
#pragma unroll
  for (int off = 32; off > 0; off >>= 1) lsum += __shfl_xor(lsum, off);
  if ((t & 63) == 0) greds[t >> 6] = lsum;
  __syncthreads();
  const float gsum = greds[0] + greds[1] + greds[2] + greds[3];

  // ---- heads: lane k in 16-lane group g accumulates over n = g + 16*i
  float hacc[MM] = {0.f, 0.f, 0.f, 0.f, 0.f};
  {
    const int k = t & 15, g = t >> 4;
    const float* gvb = gV + (size_t)(h * BB + b) * (NN * KSZ);
    for (int n = g; n < NN; n += 16) {
      const float v = gvb[n * KSZ + k];
#pragma unroll
      for (int m = 0; m < MM; ++m) hacc[m] = fmaf(comp[m][n], v, hacc[m]);
    }
  }
  // ---- AF[m][f] = sum_n e[m,n]*ndf[b,m,n,f]; lane f in 8-lane group g2
  float afv[MM] = {0.f, 0.f, 0.f, 0.f, 0.f};
  {
    const int f = t & 7, g2 = t >> 3;
    for (int n = g2; n < NN; n += 32) {
#pragma unroll
      for (int m = 0; m < MM; ++m)
        afv[m] = fmaf(comp[m][n], ndf[((size_t)(b * MM + m) * NN + n) * 8 + f], afv[m]);
    }
  }
#pragma unroll
  for (int m = 0; m < MM; ++m) {
    hacc[m] += __shfl_xor(hacc[m], 16);
    hacc[m] += __shfl_xor(hacc[m], 32);
    afv[m] += __shfl_xor(afv[m], 8);
    afv[m] += __shfl_xor(afv[m], 16);
    afv[m] += __shfl_xor(afv[m], 32);
  }
  const int w = t >> 6, lane = t & 63;
  if (lane < KSZ) {
#pragma unroll
    for (int m = 0; m < MM; ++m) red[w][m][lane] = hacc[m];
  }
  if (lane < 8) {
#pragma unroll
    for (int m = 0; m < MM; ++m) redaf[w][m][lane] = afv[m];
  }
  __syncthreads();
  if (t < MM * 8) {
    const int m = t >> 3, f = t & 7;
    afs[m][f] = redaf[0][m][f] + redaf[1][m][f] + redaf[2][m][f] + redaf[3][m][f];
  }
  __syncthreads();
  if (t < MM * KSZ) {
    const int m = t >> 4, k = t & 15;
    const float hv = red[0][m][k] + red[1][m][k] + red[2][m][k] + red[3][m][k];
    float cf = 0.f;
#pragma unroll
    for (int f = 0; f < 8; ++f)
      cf = fmaf(wpns[(h * KSZ + k) * 8 + f], afs[m][f], cf);
    conc[(b * MM + m) * DD + h * KSZ + k] = (hv + cf) / gsum;
  }
}

// One block per (b, n-chunk): final_Q, FW, logits+tanh+mask, chunk max/sumexp
__global__ __launch_bounds__(256) void k3_logits(
    const float* __restrict__ ndf, const float* __restrict__ lK,
    const int* __restrict__ mask, const float* __restrict__ wpns,
    const float* __restrict__ po, const float* __restrict__ conc,
    float* __restrict__ ews, float* __restrict__ stats)
{
  const int b = blockIdx.x >> 2;
  const int c = blockIdx.x & 3;
  const int t = threadIdx.x;
  __shared__ __align__(16) float cs[MM * DD];
  __shared__ __align__(16) float fqs[MM][DD];
  __shared__ float fw[MM][8];
  __shared__ float lg[MM][CHUNK];
  __shared__ float gredm[4];
  __shared__ float greds[4];

  for (int i = t; i < MM * DD; i += 256) cs[i] = conc[b * MM * DD + i];
  __syncthreads();
  for (int idx = t; idx < MM * DD; idx += 256) {
    const int m = idx >> 7, d = idx & 127;
    const float4* pr = (const float4*)(po + d * DD);
    const float4* cm = (const float4*)(cs + m * DD);
    float acc = 0.f;
#pragma unroll
    for (int j = 0; j < DD / 4; ++j) {
      const float4 a = pr[j], bv = cm[j];
      acc += a.x * bv.x + a.y * bv.y + a.z * bv.z + a.w * bv.w;
    }
    fqs[m][d] = acc;
  }
  __syncthreads();
  if (t < MM * 8) {
    const int m = t >> 3, f = t & 7;
    float acc = 0.f;
    for (int d = 0; d < DD; ++d)
      acc = fmaf(fqs[m][d], wpns[(2 * DD + d) * 8 + f], acc);
    fw[m][f] = acc;
  }
  __syncthreads();

  // lane k (16-lane groups), fq held in regs: fqr[m][jj] = fqs[m][jj*16+k]
  const int k = t & 15, g = t >> 4;
  float fqr[MM][8];
#pragma unroll
  for (int m = 0; m < MM; ++m)
#pragma unroll
    for (int jj = 0; jj < 8; ++jj) fqr[m][jj] = fqs[m][jj * 16 + k];

  for (int nl = g; nl < CHUNK; nl += 16) {
    const int n = c * CHUNK + nl;
    const float* lkr = lK + ((size_t)b * NN + n) * DD;
    float lkg[8];
#pragma unroll
    for (int jj = 0; jj < 8; ++jj) lkg[jj] = lkr[jj * 16 + k];
#pragma unroll
    for (int m = 0; m < MM; ++m) {
      float p = 0.f;
#pragma unroll
      for (int jj = 0; jj < 8; ++jj) p = fmaf(lkg[jj], fqr[m][jj], p);
      if (k < 8) p = fmaf(ndf[((size_t)(b * MM + m) * NN + n) * 8 + k], fw[m][k], p);
#pragma unroll
      for (int off = 8; off > 0; off >>= 1) p += __shfl_xor(p, off);
      float lgt = tanh_fast(p * INV_SQRT_D) * 10.f;
      const int mk = mask[(b * MM + m) * NN + n];
      lgt += mk ? 0.f : -1e30f;
      if (k == 0) lg[m][nl] = lgt;
    }
  }
  __syncthreads();
  const float* lgf = &lg[0][0];
  float lmax = -3e38f;
  for (int idx = t; idx < MM * CHUNK; idx += 256) lmax = fmaxf(lmax, lgf[idx]);
#pragma unroll
  for (int off = 32; off > 0; off >>= 1)
    lmax = fmaxf(lmax, __shfl_xor(lmax, off));
  if ((t & 63) == 0) gredm[t >> 6] = lmax;
  __syncthreads();
  const float cmax = fmaxf(fmaxf(gredm[0], gredm[1]), fmaxf(gredm[2], gredm[3]));
  float lsum = 0.f;
  for (int idx = t; idx < MM * CHUNK; idx += 256) {
    const int m = idx / CHUNK, nl = idx - m * CHUNK;
    const float e = __expf(lgf[idx] - cmax);
    lsum += e;
    ews[(size_t)b * (MM * NN) + m * NN + c * CHUNK + nl] = e;
  }
#pragma unroll
  for (int off = 32; off > 0; off >>= 1) lsum += __shfl_xor(lsum, off);
  if ((t & 63) == 0) greds[t >> 6] = lsum;
  __syncthreads();
  if (t == 0) {
    stats[(b * NC + c) * 2] = cmax;
    stats[(b * NC + c) * 2 + 1] = greds[0] + greds[1] + greds[2] + greds[3];
  }
}

// Combine per-chunk stats, write probs
__global__ __launch_bounds__(256) void k4_probs(
    const float* __restrict__ ews, const float* __restrict__ stats,
    float* __restrict__ out)
{
  const int b = blockIdx.x >> 2;
  const int c = blockIdx.x & 3;
  const int t = threadIdx.x;
  const float m0 = stats[b * 8 + 0], s0 = stats[b * 8 + 1];
  const float m1 = stats[b * 8 + 2], s1 = stats[b * 8 + 3];
  const float m2 = stats[b * 8 + 4], s2 = stats[b * 8 + 5];
  const float m3 = stats[b * 8 + 6], s3 = stats[b * 8 + 7];
  const float gmax = fmaxf(fmaxf(m0, m1), fmaxf(m2, m3));
  const float gsum = s0 * __expf(m0 - gmax) + s1 * __expf(m1 - gmax)
                   + s2 * __expf(m2 - gmax) + s3 * __expf(m3 - gmax);
  const float mc = stats[(b * NC + c) * 2];
  const float scale = __expf(mc - gmax) / gsum;
  for (int idx = t; idx < MM * CHUNK; idx += 256) {
    const int m = idx / CHUNK, nl = idx - m * CHUNK;
    const size_t o = (size_t)b * (MM * NN) + m * NN + c * CHUNK + nl;
    out[o] = ews[o] * scale;
  }
}

extern "C" void kernel_launch(void* const* d_in, const int* in_sizes, int n_in,
                              void* d_out, int out_size, void* d_ws, size_t ws_size,
                              hipStream_t stream) {
  // d_in[0] = node_embeddings: dead input, never read.
  const float* fc   = (const float*)d_in[1];
  const float* pne  = (const float*)d_in[2];
  const float* ndf  = (const float*)d_in[3];
  const float* vdf  = (const float*)d_in[4];
  const float* gV   = (const float*)d_in[5];
  const float* gK   = (const float*)d_in[6];
  const float* lK   = (const float*)d_in[7];
  const int*   mask = (const int*)d_in[8];
  const float* wpcv = (const float*)d_in[9];
  const float* wpns = (const float*)d_in[10];
  const float* po   = (const float*)d_in[11];

  float* conc  = (float*)d_ws;                 // B*M*D = 40960 floats
  float* ews   = conc + BB * MM * DD;          // B*M*N = 320000 floats
  float* stats = ews + BB * MM * NN;           // B*NC*2 = 512 floats
  float* out   = (float*)d_out;

  k2_attn<<<HH * BB, 256, 0, stream>>>(fc, pne, vdf, ndf, gV, gK, mask, wpcv, wpns, conc);
  k3_logits<<<BB * NC, 256, 0, stream>>>(ndf, lK, mask, wpns, po, conc, ews, stats);
  k4_probs<<<BB * NC, 256, 0, stream>>>(ews, stats, out);
}

// Round 2
// 91.597 us; speedup vs baseline: 1.5169x; 1.5169x over previous
//
#include <hip/hip_runtime.h>
#include <cstddef>

#define BB 64
#define MM 5
#define NN 1000
#define DD 128
#define HH 8
#define KSZ 16
#define NCH 4        // k2 attention chunks per (b,h)
#define CH2 250      // k2 chunk size
#define NC3 8        // k3 chunks per b
#define CH3 125      // k3 chunk size
#define INV_SQRT_D 0.08838834764831845f

__device__ __forceinline__ float tanh_fast(float x) {
  float e = __expf(2.f * x);
  return 1.f - 2.f / (e + 1.f);   // safe at +/-inf
}

// ---------------- k1: per-b query projection (prescaled by 1/sqrt(KS)=0.25)
// q_ws[b][m][d] = 0.25*(fc + [pne|vdf] @ W_pcv.T)
// qw_ws[b][h][m][f] = sum_k q[m][h*16+k] * W_pns[128+h*16+k][f]
__global__ __launch_bounds__(256) void k1_query(
    const float* __restrict__ fc, const float* __restrict__ pne,
    const float* __restrict__ vdf, const float* __restrict__ wpcv,
    const float* __restrict__ wpns, float* __restrict__ q_ws,
    float* __restrict__ qw_ws)
{
  const int b = blockIdx.x;
  const int t = threadIdx.x;
  __shared__ float wp[DD * 131];       // 67 KB staged W_pcv
  __shared__ float pn[MM][DD];
  __shared__ float vd[MM][3];
  __shared__ float fcb[DD];
  __shared__ float qsh[MM][DD];

  for (int i = t; i < DD * 131; i += 256) wp[i] = wpcv[i];
  for (int i = t; i < MM * DD; i += 256) pn[i >> 7][i & 127] = pne[b * MM * DD + i];
  if (t < MM * 3) vd[t / 3][t % 3] = vdf[b * MM * 3 + t];
  if (t >= 32 && t < 32 + DD) fcb[t - 32] = fc[b * DD + (t - 32)];
  __syncthreads();

  for (int idx = t; idx < MM * DD; idx += 256) {
    const int m = idx >> 7, d = idx & 127;
    const float* row = wp + d * 131;
    float acc = fcb[d];
#pragma unroll 8
    for (int j = 0; j < DD; ++j) acc = fmaf(pn[m][j], row[j], acc);
    acc += vd[m][0] * row[128] + vd[m][1] * row[129] + vd[m][2] * row[130];
    acc *= 0.25f;   // fold 1/sqrt(KS)
    qsh[m][d] = acc;
    q_ws[(b * MM + m) * DD + d] = acc;
  }
  __syncthreads();
  for (int idx = t; idx < HH * MM * 8; idx += 256) {
    const int h = idx / 40, r = idx % 40, m = r >> 3, f = r & 7;
    float acc = 0.f;
#pragma unroll
    for (int k = 0; k < KSZ; ++k)
      acc = fmaf(qsh[m][h * KSZ + k], wpns[(DD + h * KSZ + k) * 8 + f], acc);
    qw_ws[(b * HH + h) * 40 + m * 8 + f] = acc;
  }
}

// ---------------- k2: per (b,h,chunk) flash-style partials
// part[blk][0..79]   = sum_n e^(c-cmax) * V[n][k]        (m*16+k)
// part[blk][80..119] = sum_n e^(c-cmax) * ndf[n][f]      (m*8+f)
// part[blk][120]=cmax  part[blk][121]=csum
__global__ __launch_bounds__(256) void k2_attn(
    const float* __restrict__ ndf, const float* __restrict__ gV,
    const float* __restrict__ gK, const int* __restrict__ mask,
    const float* __restrict__ q_ws, const float* __restrict__ qw_ws,
    float* __restrict__ part)
{
  const int blk = blockIdx.x;
  const int c = blk & 3;
  const int h = (blk >> 2) & 7;
  const int b = blk >> 5;
  const int t = threadIdx.x;

  __shared__ __align__(16) float qs[MM][KSZ];
  __shared__ __align__(16) float qw[MM][8];
  __shared__ float ev[MM][CH2];
  __shared__ float red[4][MM][KSZ];
  __shared__ float redaf[4][MM][8];
  __shared__ float rm[4];
  __shared__ float rs[4];

  if (t < MM * KSZ) qs[t >> 4][t & 15] = q_ws[(b * MM + (t >> 4)) * DD + h * KSZ + (t & 15)];
  if (t >= 64 && t < 64 + MM * 8) {
    const int r = t - 64;
    qw[r >> 3][r & 7] = qw_ws[(b * HH + h) * 40 + r];
  }
  __syncthreads();

  const int n0 = c * CH2;
  float cv[MM];
  float lmax = -3e38f;
  if (t < CH2) {
    const int n = n0 + t;
    const float4* Kp = (const float4*)(gK + ((size_t)(h * BB + b) * NN + n) * KSZ);
    const float4 k0 = Kp[0], k1 = Kp[1], k2 = Kp[2], k3 = Kp[3];
#pragma unroll
    for (int m = 0; m < MM; ++m) {
      const float4* fp = (const float4*)(ndf + ((size_t)(b * MM + m) * NN + n) * 8);
      const float4 f0 = fp[0], f1 = fp[1];
      const float4* qm = (const float4*)qs[m];
      const float4 q0 = qm[0], q1 = qm[1], q2 = qm[2], q3 = qm[3];
      const float4* wm = (const float4*)qw[m];
      const float4 w0 = wm[0], w1 = wm[1];
      float dot = k0.x * q0.x + k0.y * q0.y + k0.z * q0.z + k0.w * q0.w;
      dot += k1.x * q1.x + k1.y * q1.y + k1.z * q1.z + k1.w * q1.w;
      dot += k2.x * q2.x + k2.y * q2.y + k2.z * q2.z + k2.w * q2.w;
      dot += k3.x * q3.x + k3.y * q3.y + k3.z * q3.z + k3.w * q3.w;
      dot += f0.x * w0.x + f0.y * w0.y + f0.z * w0.z + f0.w * w0.w;
      dot += f1.x * w1.x + f1.y * w1.y + f1.z * w1.z + f1.w * w1.w;
      const int mk = mask[(b * MM + m) * NN + n];
      cv[m] = dot + (mk ? 0.f : -1e30f);
      lmax = fmaxf(lmax, cv[m]);
    }
  }
#pragma unroll
  for (int off = 32; off; off >>= 1) lmax = fmaxf(lmax, __shfl_xor(lmax, off));
  if ((t & 63) == 0) rm[t >> 6] = lmax;
  __syncthreads();
  const float cmax = fmaxf(fmaxf(rm[0], rm[1]), fmaxf(rm[2], rm[3]));

  float lsum = 0.f;
  if (t < CH2) {
#pragma unroll
    for (int m = 0; m < MM; ++m) {
      const float e = __expf(cv[m] - cmax);
      ev[m][t] = e;
      lsum += e;
    }
  }
#pragma unroll
  for (int off = 32; off; off >>= 1) lsum += __shfl_xor(lsum, off);
  if ((t & 63) == 0) rs[t >> 6] = lsum;
  __syncthreads();
  const float csum = rs[0] + rs[1] + rs[2] + rs[3];

  // partial heads: 16-lane groups over n
  float hacc[MM] = {0.f, 0.f, 0.f, 0.f, 0.f};
  {
    const int k = t & 15, g = t >> 4;
    const float* gvb = gV + ((size_t)(h * BB + b) * NN + n0) * KSZ;
    for (int nl = g; nl < CH2; nl += 16) {
      const float v = gvb[nl * KSZ + k];
#pragma unroll
      for (int m = 0; m < MM; ++m) hacc[m] = fmaf(ev[m][nl], v, hacc[m]);
    }
  }
  // partial AF: 8-lane groups over n
  float afv[MM] = {0.f, 0.f, 0.f, 0.f, 0.f};
  {
    const int f = t & 7, g2 = t >> 3;
    for (int nl = g2; nl < CH2; nl += 32) {
#pragma unroll
      for (int m = 0; m < MM; ++m)
        afv[m] = fmaf(ev[m][nl], ndf[((size_t)(b * MM + m) * NN + n0 + nl) * 8 + f], afv[m]);
    }
  }
#pragma unroll
  for (int m = 0; m < MM; ++m) {
    hacc[m] += __shfl_xor(hacc[m], 16);
    hacc[m] += __shfl_xor(hacc[m], 32);
    afv[m] += __shfl_xor(afv[m], 8);
    afv[m] += __shfl_xor(afv[m], 16);
    afv[m] += __shfl_xor(afv[m], 32);
  }
  const int w = t >> 6, lane = t & 63;
  if (lane < KSZ) {
#pragma unroll
    for (int m = 0; m < MM; ++m) red[w][m][lane] = hacc[m];
  }
  if (lane < 8) {
#pragma unroll
    for (int m = 0; m < MM; ++m) redaf[w][m][lane] = afv[m];
  }
  __syncthreads();
  float* P = part + (size_t)blk * 128;
  if (t < MM * KSZ) {
    const int m = t >> 4, k = t & 15;
    P[m * 16 + k] = red[0][m][k] + red[1][m][k] + red[2][m][k] + red[3][m][k];
  } else if (t >= 128 && t < 128 + MM * 8) {
    const int r = t - 128, m = r >> 3, f = r & 7;
    P[80 + r] = redaf[0][m][f] + redaf[1][m][f] + redaf[2][m][f] + redaf[3][m][f];
  } else if (t == 254) {
    P[120] = cmax;
  } else if (t == 255) {
    P[121] = csum;
  }
}

// ---------------- k2b: per-b combine chunks -> conc -> fq (prescaled), fw
__global__ __launch_bounds__(256) void k2b_combine(
    const float* __restrict__ part, const float* __restrict__ wpns,
    const float* __restrict__ po, float* __restrict__ fq_ws,
    float* __restrict__ fw_ws)
{
  const int b = blockIdx.x;
  const int t = threadIdx.x;
  __shared__ float pos[DD][DD + 1];   // padded: conflict-free column reads
  __shared__ float scl[HH][NCH];
  __shared__ float gsum[HH];
  __shared__ float afs[HH][MM][8];
  __shared__ float cs[MM][DD];
  __shared__ float fqs[MM][DD];

  for (int i = t; i < DD * DD; i += 256) pos[i >> 7][i & 127] = po[i];
  if (t < HH) {
    const float* pb = part + (size_t)(b * HH + t) * NCH * 128;
    float mx = -3e38f;
#pragma unroll
    for (int c = 0; c < NCH; ++c) mx = fmaxf(mx, pb[c * 128 + 120]);
    float s = 0.f;
#pragma unroll
    for (int c = 0; c < NCH; ++c) {
      const float e = __expf(pb[c * 128 + 120] - mx);
      scl[t][c] = e;
      s += e * pb[c * 128 + 121];
    }
    gsum[t] = s;
  }
  __syncthreads();
  for (int idx = t; idx < HH * MM * 8; idx += 256) {
    const int h = idx / 40, r = idx % 40;
    const float* pb = part + (size_t)(b * HH + h) * NCH * 128;
    float a = 0.f;
#pragma unroll
    for (int c = 0; c < NCH; ++c) a += scl[h][c] * pb[c * 128 + 80 + r];
    afs[h][r >> 3][r & 7] = a;
  }
  __syncthreads();
  for (int idx = t; idx < MM * DD; idx += 256) {
    const int m = idx >> 7, d = idx & 127;
    const int h = d >> 4;
    const float* pb = part + (size_t)(b * HH + h) * NCH * 128;
    float a = 0.f;
#pragma unroll
    for (int c = 0; c < NCH; ++c) a += scl[h][c] * pb[c * 128 + m * 16 + (d & 15)];
    float cf = 0.f;
#pragma unroll
    for (int f = 0; f < 8; ++f) cf = fmaf(wpns[d * 8 + f], afs[h][m][f], cf);
    cs[m][d] = (a + cf) / gsum[h];
  }
  __syncthreads();
  for (int idx = t; idx < MM * DD; idx += 256) {
    const int m = idx >> 7, d = idx & 127;
    float acc = 0.f;
#pragma unroll 8
    for (int j = 0; j < DD; ++j) acc = fmaf(cs[m][j], pos[d][j], acc);
    acc *= INV_SQRT_D;   // fold 1/sqrt(D)
    fqs[m][d] = acc;
    fq_ws[(b * MM + m) * DD + d] = acc;
  }
  __syncthreads();
  if (t < MM * 8) {
    const int m = t >> 3, f = t & 7;
    float acc = 0.f;
#pragma unroll 16
    for (int d = 0; d < DD; ++d) acc = fmaf(fqs[m][d], wpns[(2 * DD + d) * 8 + f], acc);
    fw_ws[b * 40 + t] = acc;
  }
}

// ---------------- k3: per (b,chunk) logits -> e-values (into d_out) + stats
__global__ __launch_bounds__(256) void k3_logits(
    const float* __restrict__ ndf, const float* __restrict__ lK,
    const int* __restrict__ mask, const float* __restrict__ fq_ws,
    const float* __restrict__ fw_ws, float* __restrict__ evout,
    float* __restrict__ stats)
{
  const int b = blockIdx.x >> 3;
  const int c = blockIdx.x & 7;
  const int t = threadIdx.x;
  __shared__ __align__(16) float fqs[MM][DD];
  __shared__ float fw[MM][8];
  __shared__ float lg[MM][CH3];
  __shared__ float rm[4];
  __shared__ float rs[4];

  for (int i = t; i < MM * DD; i += 256) fqs[i >> 7][i & 127] = fq_ws[b * MM * DD + i];
  if (t < MM * 8) fw[t >> 3][t & 7] = fw_ws[b * 40 + t];
  __syncthreads();

  const int k = t & 15, g = t >> 4;
  float fqr[MM][8];
#pragma unroll
  for (int m = 0; m < MM; ++m)
#pragma unroll
    for (int jj = 0; jj < 8; ++jj) fqr[m][jj] = fqs[m][jj * 16 + k];

  const int nbase = c * CH3;
  for (int nl = g; nl < CH3; nl += 16) {
    const int n = nbase + nl;
    const float* lkr = lK + ((size_t)b * NN + n) * DD;
    float lkg[8];
#pragma unroll
    for (int jj = 0; jj < 8; ++jj) lkg[jj] = lkr[jj * 16 + k];
#pragma unroll
    for (int m = 0; m < MM; ++m) {
      float p = 0.f;
#pragma unroll
      for (int jj = 0; jj < 8; ++jj) p = fmaf(lkg[jj], fqr[m][jj], p);
      if (k < 8) p = fmaf(ndf[((size_t)(b * MM + m) * NN + n) * 8 + k], fw[m][k], p);
#pragma unroll
      for (int off = 8; off > 0; off >>= 1) p += __shfl_xor(p, off);
      float lgt = tanh_fast(p) * 10.f;
      const int mk = mask[(b * MM + m) * NN + n];
      lgt += mk ? 0.f : -1e30f;
      if (k == 0) lg[m][nl] = lgt;
    }
  }
  __syncthreads();
  const float* lgf = &lg[0][0];
  float lmax = -3e38f;
  for (int i = t; i < MM * CH3; i += 256) lmax = fmaxf(lmax, lgf[i]);
#pragma unroll
  for (int off = 32; off; off >>= 1) lmax = fmaxf(lmax, __shfl_xor(lmax, off));
  if ((t & 63) == 0) rm[t >> 6] = lmax;
  __syncthreads();
  const float cmax = fmaxf(fmaxf(rm[0], rm[1]), fmaxf(rm[2], rm[3]));
  float lsum = 0.f;
  for (int i = t; i < MM * CH3; i += 256) {
    const int m = i / CH3, nl = i - m * CH3;
    const float e = __expf(lgf[i] - cmax);
    lsum += e;
    evout[(size_t)b * (MM * NN) + m * NN + nbase + nl] = e;
  }
#pragma unroll
  for (int off = 32; off; off >>= 1) lsum += __shfl_xor(lsum, off);
  if ((t & 63) == 0) rs[t >> 6] = lsum;
  __syncthreads();
  if (t == 0) {
    stats[(b * NC3 + c) * 2] = cmax;
    stats[(b * NC3 + c) * 2 + 1] = rs[0] + rs[1] + rs[2] + rs[3];
  }
}

// ---------------- k4: combine chunk stats, scale e-values in place
__global__ __launch_bounds__(256) void k4_probs(
    const float* __restrict__ stats, float* __restrict__ out)
{
  const int b = blockIdx.x >> 3;
  const int c = blockIdx.x & 7;
  const int t = threadIdx.x;
  float gmax = -3e38f;
#pragma unroll
  for (int cc = 0; cc < NC3; ++cc) gmax = fmaxf(gmax, stats[(b * NC3 + cc) * 2]);
  float gs = 0.f;
#pragma unroll
  for (int cc = 0; cc < NC3; ++cc)
    gs += stats[(b * NC3 + cc) * 2 + 1] * __expf(stats[(b * NC3 + cc) * 2] - gmax);
  const float scale = __expf(stats[(b * NC3 + c) * 2] - gmax) / gs;
  const int nbase = c * CH3;
  for (int i = t; i < MM * CH3; i += 256) {
    const int m = i / CH3, nl = i - m * CH3;
    const size_t o = (size_t)b * (MM * NN) + m * NN + nbase + nl;
    out[o] = out[o] * scale;
  }
}

extern "C" void kernel_launch(void* const* d_in, const int* in_sizes, int n_in,
                              void* d_out, int out_size, void* d_ws, size_t ws_size,
                              hipStream_t stream) {
  // d_in[0] = node_embeddings: dead input, never read.
  const float* fc   = (const float*)d_in[1];
  const float* pne  = (const float*)d_in[2];
  const float* ndf  = (const float*)d_in[3];
  const float* vdf  = (const float*)d_in[4];
  const float* gV   = (const float*)d_in[5];
  const float* gK   = (const float*)d_in[6];
  const float* lK   = (const float*)d_in[7];
  const int*   mask = (const int*)d_in[8];
  const float* wpcv = (const float*)d_in[9];
  const float* wpns = (const float*)d_in[10];
  const float* po   = (const float*)d_in[11];

  float* q_ws  = (float*)d_ws;                     // 40960
  float* qw_ws = q_ws + BB * MM * DD;              // 20480
  float* part  = qw_ws + BB * HH * MM * 8;         // 2048*128 = 262144
  float* fq_ws = part + (size_t)BB * HH * NCH * 128; // 40960
  float* fw_ws = fq_ws + BB * MM * DD;             // 2560
  float* stats = fw_ws + BB * 40;                  // 1024
  float* out   = (float*)d_out;

  k1_query<<<BB, 256, 0, stream>>>(fc, pne, vdf, wpcv, wpns, q_ws, qw_ws);
  k2_attn<<<BB * HH * NCH, 256, 0, stream>>>(ndf, gV, gK, mask, q_ws, qw_ws, part);
  k2b_combine<<<BB, 256, 0, stream>>>(part, wpns, po, fq_ws, fw_ws);
  k3_logits<<<BB * NC3, 256, 0, stream>>>(ndf, lK, mask, fq_ws, fw_ws, out, stats);
  k4_probs<<<BB * NC3, 256, 0, stream>>>(stats, out);
}

// Round 4
// 62.252 us; speedup vs baseline: 2.2320x; 1.4714x over previous
//
#include <hip/hip_runtime.h>
#include <cstddef>

#define BB 64
#define MM 5
#define NN 1000
#define DD 128
#define HH 8
#define KSZ 16
#define NCH 4        // k2 attention chunks per (b,h)
#define CH2 250      // k2 chunk size
#define NC3 8        // k3 chunks per b
#define CH3 125      // k3 chunk size
#define INV_SQRT_D 0.08838834764831845f

__device__ __forceinline__ float tanh_fast(float x) {
  float e = __expf(2.f * x);
  return 1.f - 2.f / (e + 1.f);   // safe at +/-inf
}

// ---------------- k1: per-(b,m) query projection via 16-lane shfl-dot.
// q_ws[b][m][d] = 0.25*(fc[d] + [pne|vdf] . W_pcv[d])   (prescaled by 1/sqrt(KS))
// qw_ws[b][h][m][f] = sum_k q[m][h*16+k] * W_pns[128+h*16+k][f]
__global__ __launch_bounds__(256) void k1_query(
    const float* __restrict__ fc, const float* __restrict__ pne,
    const float* __restrict__ vdf, const float* __restrict__ wpcv,
    const float* __restrict__ wpns, float* __restrict__ q_ws,
    float* __restrict__ qw_ws)
{
  const int bm = blockIdx.x;            // b*5 + m
  const int b = bm / MM;
  const int m = bm % MM;
  const int t = threadIdx.x;
  const int k = t & 15, gid = t >> 4;   // 16 groups of 16 lanes
  __shared__ float qsh[DD];

  // lane-resident cvs slice: cvs[j], j = k + 16*jp
  float cvr[9];
  const float* pner = pne + (size_t)bm * DD;
#pragma unroll
  for (int jp = 0; jp < 8; ++jp) cvr[jp] = pner[k + 16 * jp];
  cvr[8] = (k < 3) ? vdf[bm * 3 + k] : 0.f;

#pragma unroll 2
  for (int dd = 0; dd < 8; ++dd) {
    const int d = gid + 16 * dd;
    const float* wrow = wpcv + d * 131;
    float p = 0.f;
#pragma unroll
    for (int jp = 0; jp < 8; ++jp) p = fmaf(cvr[jp], wrow[k + 16 * jp], p);
    if (k < 3) p = fmaf(cvr[8], wrow[128 + k], p);
    p += __shfl_xor(p, 1); p += __shfl_xor(p, 2);
    p += __shfl_xor(p, 4); p += __shfl_xor(p, 8);
    if (k == 0) {
      const float q = 0.25f * (p + fc[b * DD + d]);
      qsh[d] = q;
      q_ws[(size_t)bm * DD + d] = q;
    }
  }
  __syncthreads();
  if (t < 64) {
    const int h = t >> 3, f = t & 7;
    float acc = 0.f;
#pragma unroll
    for (int kk = 0; kk < KSZ; ++kk)
      acc = fmaf(qsh[h * KSZ + kk], wpns[(DD + h * KSZ + kk) * 8 + f], acc);
    qw_ws[(b * HH + h) * 40 + m * 8 + f] = acc;
  }
}

// ---------------- k2: per (b,h,chunk) single-pass attention partials.
// 8-lane groups: lane k holds K/V elems 2k,2k+1 and ndf feature f=k.
// part[blk][m*16+kk] = sum_n e * V[n][kk];  part[blk][80+m*8+f] = sum_n e*ndf[n][f];
// part[blk][120] = sum e.   (direct exp, no max — values bounded ~|7|)
__global__ __launch_bounds__(256) void k2_attn(
    const float* __restrict__ ndf, const float* __restrict__ gV,
    const float* __restrict__ gK, const int* __restrict__ mask,
    const float* __restrict__ q_ws, const float* __restrict__ qw_ws,
    float* __restrict__ part)
{
  const int blk = blockIdx.x;
  const int c = blk & 3;
  const int h = (blk >> 2) & 7;
  const int b = blk >> 5;
  const int t = threadIdx.x;
  const int k = t & 7, gid = t >> 3;    // 32 groups of 8 lanes
  const int n0 = c * CH2;

  float2 qr[MM];
  float qwr[MM];
#pragma unroll
  for (int m = 0; m < MM; ++m) {
    qr[m] = *(const float2*)(q_ws + (size_t)(b * MM + m) * DD + h * KSZ + 2 * k);
    qwr[m] = qw_ws[(b * HH + h) * 40 + m * 8 + k];
  }
  float2 hacc[MM] = {};
  float afv[MM] = {};
  float lsum = 0.f;

  const float* kbase = gK + ((size_t)(h * BB + b) * NN + n0) * KSZ;
  const float* vbase = gV + ((size_t)(h * BB + b) * NN + n0) * KSZ;
  const float* nbase = ndf + (size_t)(b * MM) * NN * 8;
  const int* mbase = mask + (size_t)(b * MM) * NN;

  auto body = [&](int nl) {
    const float2 kv = *(const float2*)(kbase + nl * KSZ + 2 * k);
    const float2 vv = *(const float2*)(vbase + nl * KSZ + 2 * k);
    float ndv[MM]; int mk[MM];
#pragma unroll
    for (int m = 0; m < MM; ++m) {
      const size_t roff = (size_t)m * NN + n0 + nl;
      ndv[m] = nbase[roff * 8 + k];
      mk[m] = mbase[roff];
    }
#pragma unroll
    for (int m = 0; m < MM; ++m) {
      float p = kv.x * qr[m].x + kv.y * qr[m].y + ndv[m] * qwr[m];
      p += __shfl_xor(p, 1); p += __shfl_xor(p, 2); p += __shfl_xor(p, 4);
      const float e = mk[m] ? __expf(p) : 0.f;
      hacc[m].x = fmaf(e, vv.x, hacc[m].x);
      hacc[m].y = fmaf(e, vv.y, hacc[m].y);
      afv[m] = fmaf(e, ndv[m], afv[m]);
      lsum += e;
    }
  };

#pragma unroll 2
  for (int i = 0; i < 7; ++i) body(gid + 32 * i);
  if (gid + 224 < CH2) body(gid + 224);   // group-uniform branch

  // butterfly across the 8 groups of each wave (same k-component exchanged)
#pragma unroll
  for (int m = 0; m < MM; ++m) {
    hacc[m].x += __shfl_xor(hacc[m].x, 8);
    hacc[m].x += __shfl_xor(hacc[m].x, 16);
    hacc[m].x += __shfl_xor(hacc[m].x, 32);
    hacc[m].y += __shfl_xor(hacc[m].y, 8);
    hacc[m].y += __shfl_xor(hacc[m].y, 16);
    hacc[m].y += __shfl_xor(hacc[m].y, 32);
    afv[m] += __shfl_xor(afv[m], 8);
    afv[m] += __shfl_xor(afv[m], 16);
    afv[m] += __shfl_xor(afv[m], 32);
  }
  lsum += __shfl_xor(lsum, 8);
  lsum += __shfl_xor(lsum, 16);
  lsum += __shfl_xor(lsum, 32);

  __shared__ float redh[4][MM][KSZ];
  __shared__ float redaf[4][MM][8];
  __shared__ float reds[4];
  const int w = t >> 6;
  if ((t & 63) < 8) {
    const int kk = t & 7;
#pragma unroll
    for (int m = 0; m < MM; ++m) {
      redh[w][m][2 * kk] = hacc[m].x;
      redh[w][m][2 * kk + 1] = hacc[m].y;
      redaf[w][m][kk] = afv[m];
    }
  }
  if ((t & 63) == 0) reds[w] = lsum;
  __syncthreads();
  float* P = part + (size_t)blk * 128;
  if (t < 80) {
    const int m = t >> 4, kk = t & 15;
    P[t] = redh[0][m][kk] + redh[1][m][kk] + redh[2][m][kk] + redh[3][m][kk];
  } else if (t < 120) {
    const int r = t - 80, m = r >> 3, f = r & 7;
    P[80 + r] = redaf[0][m][f] + redaf[1][m][f] + redaf[2][m][f] + redaf[3][m][f];
  } else if (t == 120) {
    P[120] = reds[0] + reds[1] + reds[2] + reds[3];
  }
}

// ---------------- k2b: per-b combine (plain sums now) -> conc -> fq, fw
__global__ __launch_bounds__(256) void k2b_combine(
    const float* __restrict__ part, const float* __restrict__ wpns,
    const float* __restrict__ po, float* __restrict__ fq_ws,
    float* __restrict__ fw_ws)
{
  const int b = blockIdx.x;
  const int t = threadIdx.x;
  __shared__ float pos[DD][129];   // stride 129: conflict-free column reads
  __shared__ float rgs[HH];
  __shared__ float afs[HH][MM][8];
  __shared__ float cs[MM][DD];
  __shared__ float fqs[MM][DD];

  for (int i = t; i < DD * DD / 4; i += 256) {
    const float4 v = ((const float4*)po)[i];
    const int r = (i * 4) >> 7, cc = (i * 4) & 127;
    pos[r][cc] = v.x; pos[r][cc + 1] = v.y; pos[r][cc + 2] = v.z; pos[r][cc + 3] = v.w;
  }
  const float* pb = part + (size_t)b * 32 * 128;   // 32 chunks: (h*4+c)
  if (t < HH) {
    float s = 0.f;
#pragma unroll
    for (int c = 0; c < NCH; ++c) s += pb[(t * 4 + c) * 128 + 120];
    rgs[t] = 1.f / s;
  }
  for (int idx = t; idx < HH * MM * 8; idx += 256) {
    const int h = idx / 40, r = idx % 40;
    float a = 0.f;
#pragma unroll
    for (int c = 0; c < NCH; ++c) a += pb[(h * 4 + c) * 128 + 80 + r];
    afs[h][r >> 3][r & 7] = a;
  }
  __syncthreads();
  for (int idx = t; idx < MM * DD; idx += 256) {
    const int m = idx >> 7, d = idx & 127, h = d >> 4;
    float a = 0.f;
#pragma unroll
    for (int c = 0; c < NCH; ++c) a += pb[(h * 4 + c) * 128 + m * 16 + (d & 15)];
    float cf = 0.f;
#pragma unroll
    for (int f = 0; f < 8; ++f) cf = fmaf(wpns[d * 8 + f], afs[h][m][f], cf);
    cs[m][d] = (a + cf) * rgs[h];
  }
  __syncthreads();
  for (int idx = t; idx < MM * DD; idx += 256) {
    const int m = idx >> 7, d = idx & 127;
    float acc = 0.f;
#pragma unroll 8
    for (int j = 0; j < DD; ++j) acc = fmaf(cs[m][j], pos[d][j], acc);
    acc *= INV_SQRT_D;   // fold 1/sqrt(D)
    fqs[m][d] = acc;
    fq_ws[(size_t)b * (MM * DD) + idx] = acc;
  }
  __syncthreads();
  if (t < MM * 8) {
    const int m = t >> 3, f = t & 7;
    float acc = 0.f;
#pragma unroll 16
    for (int d = 0; d < DD; ++d) acc = fmaf(fqs[m][d], wpns[(2 * DD + d) * 8 + f], acc);
    fw_ws[b * 40 + t] = acc;
  }
}

// ---------------- k3: per (b,chunk) logits via 16-lane shfl-dot, direct exp.
// Writes e-values to out, per-chunk sum to stats.
__global__ __launch_bounds__(512) void k3_logits(
    const float* __restrict__ ndf, const float* __restrict__ lK,
    const int* __restrict__ mask, const float* __restrict__ fq_ws,
    const float* __restrict__ fw_ws, float* __restrict__ out,
    float* __restrict__ stats)
{
  const int b = blockIdx.x >> 3;
  const int c = blockIdx.x & 7;
  const int t = threadIdx.x;
  const int k = t & 15, gid = t >> 4;   // 32 groups of 16 lanes
  const int n0 = c * CH3;

  float2 fqr[MM][4];
  float fwr[MM];
#pragma unroll
  for (int m = 0; m < MM; ++m) {
#pragma unroll
    for (int jp = 0; jp < 4; ++jp)
      fqr[m][jp] = *(const float2*)(fq_ws + (size_t)(b * MM + m) * DD + 32 * jp + 2 * k);
    fwr[m] = fw_ws[b * 40 + m * 8 + (k & 7)];
  }
  float lsum = 0.f;

#pragma unroll
  for (int i = 0; i < 4; ++i) {
    const int nl = gid + 32 * i;
    const bool valid = (nl < CH3);          // group-uniform
    const int n = n0 + (valid ? nl : 0);
    const float* lkr = lK + ((size_t)b * NN + n) * DD;
    const float2 lk0 = *(const float2*)(lkr + 2 * k);
    const float2 lk1 = *(const float2*)(lkr + 32 + 2 * k);
    const float2 lk2 = *(const float2*)(lkr + 64 + 2 * k);
    const float2 lk3 = *(const float2*)(lkr + 96 + 2 * k);
    float ndv[MM]; int mk[MM];
#pragma unroll
    for (int m = 0; m < MM; ++m) {
      const size_t roff = (size_t)(b * MM + m) * NN + n;
      ndv[m] = ndf[roff * 8 + (k & 7)];
      mk[m] = mask[roff];
    }
#pragma unroll
    for (int m = 0; m < MM; ++m) {
      float p = lk0.x * fqr[m][0].x + lk0.y * fqr[m][0].y
              + lk1.x * fqr[m][1].x + lk1.y * fqr[m][1].y
              + lk2.x * fqr[m][2].x + lk2.y * fqr[m][2].y
              + lk3.x * fqr[m][3].x + lk3.y * fqr[m][3].y;
      p += (k < 8) ? ndv[m] * fwr[m] : 0.f;
      p += __shfl_xor(p, 1); p += __shfl_xor(p, 2);
      p += __shfl_xor(p, 4); p += __shfl_xor(p, 8);
      const float e = mk[m] ? __expf(tanh_fast(p) * 10.f) : 0.f;
      if (valid) {
        lsum += e;
        if (k == 0) out[(size_t)(b * MM + m) * NN + n] = e;
      }
    }
  }
  // per-lane lsum is already the group's sum (each lane holds a copy; no
  // intra-group summation happens). xor16/32 sums the 4 groups of the wave.
  lsum += __shfl_xor(lsum, 16);
  lsum += __shfl_xor(lsum, 32);
  __shared__ float wred[8];
  if ((t & 63) == 0) wred[t >> 6] = lsum;
  __syncthreads();
  if (t == 0) {
    float s = 0.f;
#pragma unroll
    for (int w = 0; w < 8; ++w) s += wred[w];
    stats[b * NC3 + c] = s;
  }
}

// ---------------- k4: per (b,m) scale row by 1/sum
__global__ __launch_bounds__(256) void k4_probs(
    const float* __restrict__ stats, float* __restrict__ out)
{
  const int bm = blockIdx.x;
  const int b = bm / MM;
  const int t = threadIdx.x;
  float s = 0.f;
#pragma unroll
  for (int c = 0; c < NC3; ++c) s += stats[b * NC3 + c];
  const float scale = 1.f / s;
  if (t < 250) {
    float4* p = (float4*)(out + (size_t)bm * NN);
    float4 v = p[t];
    v.x *= scale; v.y *= scale; v.z *= scale; v.w *= scale;
    p[t] = v;
  }
}

extern "C" void kernel_launch(void* const* d_in, const int* in_sizes, int n_in,
                              void* d_out, int out_size, void* d_ws, size_t ws_size,
                              hipStream_t stream) {
  // d_in[0] = node_embeddings: dead input, never read.
  const float* fc   = (const float*)d_in[1];
  const float* pne  = (const float*)d_in[2];
  const float* ndf  = (const float*)d_in[3];
  const float* vdf  = (const float*)d_in[4];
  const float* gV   = (const float*)d_in[5];
  const float* gK   = (const float*)d_in[6];
  const float* lK   = (const float*)d_in[7];
  const int*   mask = (const int*)d_in[8];
  const float* wpcv = (const float*)d_in[9];
  const float* wpns = (const float*)d_in[10];
  const float* po   = (const float*)d_in[11];

  float* q_ws  = (float*)d_ws;                       // 40960
  float* qw_ws = q_ws + BB * MM * DD;                // 20480
  float* part  = qw_ws + BB * HH * MM * 8;           // 2048*128
  float* fq_ws = part + (size_t)BB * HH * NCH * 128; // 40960
  float* fw_ws = fq_ws + BB * MM * DD;               // 2560
  float* stats = fw_ws + BB * 40;                    // 512
  float* out   = (float*)d_out;

  k1_query<<<BB * MM, 256, 0, stream>>>(fc, pne, vdf, wpcv, wpns, q_ws, qw_ws);
  k2_attn<<<BB * HH * NCH, 256, 0, stream>>>(ndf, gV, gK, mask, q_ws, qw_ws, part);
  k2b_combine<<<BB, 256, 0, stream>>>(part, wpns, po, fq_ws, fw_ws);
  k3_logits<<<BB * NC3, 512, 0, stream>>>(ndf, lK, mask, fq_ws, fw_ws, out, stats);
  k4_probs<<<BB * MM, 256, 0, stream>>>(stats, out);
}

// Round 5
// 58.849 us; speedup vs baseline: 2.3610x; 1.0578x over previous
//
#include <hip/hip_runtime.h>
#include <cstddef>

#define BB 64
#define MM 5
#define NN 1000
#define DD 128
#define HH 8
#define KSZ 16
#define NCH 4        // k2 attention chunks per (b,h)
#define CH2 250      // k2 chunk size
#define NC3 8        // k3 chunks per b
#define CH3 125      // k3 chunk size
#define INV_SQRT_D 0.08838834764831845f

__device__ __forceinline__ float tanh_fast(float x) {
  float e = __expf(2.f * x);
  return 1.f - 2.f / (e + 1.f);   // safe at +/-inf
}

// ---------------- k1: blocks [0,320): per-(b,m) query projection via 16-lane
// shfl-dot; blocks [320,384): pack feasibility mask bits -> pmask[b][n].
// q_ws[b][m][d] = 0.25*(fc[d] + [pne|vdf] . W_pcv[d])   (prescaled by 1/sqrt(KS))
// qw_ws[b][h][m][f] = sum_k q[m][h*16+k] * W_pns[128+h*16+k][f]
__global__ __launch_bounds__(256) void k1_query(
    const float* __restrict__ fc, const float* __restrict__ pne,
    const float* __restrict__ vdf, const float* __restrict__ wpcv,
    const float* __restrict__ wpns, const int* __restrict__ mask,
    float* __restrict__ q_ws, float* __restrict__ qw_ws,
    unsigned int* __restrict__ pmask)
{
  const int t = threadIdx.x;
  if (blockIdx.x >= BB * MM) {          // mask-pack blocks
    const int b = blockIdx.x - BB * MM;
    const int* mb = mask + (size_t)(b * MM) * NN;
    for (int n = t; n < NN; n += 256) {
      unsigned int pm = 0;
#pragma unroll
      for (int m = 0; m < MM; ++m) pm |= (mb[m * NN + n] != 0 ? 1u : 0u) << m;
      pmask[b * NN + n] = pm;
    }
    return;
  }
  const int bm = blockIdx.x;            // b*5 + m
  const int b = bm / MM;
  const int k = t & 15, gid = t >> 4;   // 16 groups of 16 lanes
  __shared__ float qsh[DD];

  // lane-resident cvs slice: cvs[j], j = k + 16*jp
  float cvr[9];
  const float* pner = pne + (size_t)bm * DD;
#pragma unroll
  for (int jp = 0; jp < 8; ++jp) cvr[jp] = pner[k + 16 * jp];
  cvr[8] = (k < 3) ? vdf[bm * 3 + k] : 0.f;

#pragma unroll 2
  for (int dd = 0; dd < 8; ++dd) {
    const int d = gid + 16 * dd;
    const float* wrow = wpcv + d * 131;
    float p = 0.f;
#pragma unroll
    for (int jp = 0; jp < 8; ++jp) p = fmaf(cvr[jp], wrow[k + 16 * jp], p);
    if (k < 3) p = fmaf(cvr[8], wrow[128 + k], p);
    p += __shfl_xor(p, 1); p += __shfl_xor(p, 2);
    p += __shfl_xor(p, 4); p += __shfl_xor(p, 8);
    if (k == 0) {
      const float q = 0.25f * (p + fc[b * DD + d]);
      qsh[d] = q;
      q_ws[(size_t)bm * DD + d] = q;
    }
  }
  __syncthreads();
  if (t < 64) {
    const int h = t >> 3, f = t & 7;
    float acc = 0.f;
#pragma unroll
    for (int kk = 0; kk < KSZ; ++kk)
      acc = fmaf(qsh[h * KSZ + kk], wpns[(DD + h * KSZ + kk) * 8 + f], acc);
    qw_ws[(b * HH + h) * 40 + (bm % MM) * 8 + f] = acc;
  }
}

// ---------------- k2: per (b,h,chunk) single-pass attention partials.
// 4-lane groups: lane k holds K/V comps [4k,4k+4) (float4) and ndf feats 2k,2k+1.
// part[blk][m*16+kk] = sum_n e*V[n][kk]; part[blk][80+m*8+f] = sum_n e*ndf[n][f];
// part[blk][120] = sum e.   (direct exp, no max — values bounded)
__global__ __launch_bounds__(256) void k2_attn(
    const float* __restrict__ ndf, const float* __restrict__ gV,
    const float* __restrict__ gK, const unsigned int* __restrict__ pmask,
    const float* __restrict__ q_ws, const float* __restrict__ qw_ws,
    float* __restrict__ part)
{
  const int blk = blockIdx.x;
  const int c = blk & 3;
  const int h = (blk >> 2) & 7;
  const int b = blk >> 5;
  const int t = threadIdx.x;
  const int k = t & 3, gid = t >> 2;    // 64 groups of 4 lanes
  const int n0 = c * CH2;

  float4 qr[MM];
  float2 qwr[MM];
#pragma unroll
  for (int m = 0; m < MM; ++m) {
    qr[m] = *(const float4*)(q_ws + (size_t)(b * MM + m) * DD + h * KSZ + 4 * k);
    qwr[m] = *(const float2*)(qw_ws + (b * HH + h) * 40 + m * 8 + 2 * k);
  }
  float4 hacc[MM] = {};
  float2 afv[MM] = {};
  float lsum = 0.f;

  const float* kbase = gK + ((size_t)(h * BB + b) * NN + n0) * KSZ;
  const float* vbase = gV + ((size_t)(h * BB + b) * NN + n0) * KSZ;
  const float* nbase = ndf + ((size_t)(b * MM) * NN + n0) * 8;
  const unsigned int* pmb = pmask + b * NN + n0;

#pragma unroll
  for (int i = 0; i < 4; ++i) {
    const int nl = gid + 64 * i;
    const bool valid = (nl < CH2);                 // group-uniform
    const int nc = valid ? nl : 0;
    const unsigned int pm = valid ? pmb[nc] : 0u;
    const float4 kv = *(const float4*)(kbase + nc * KSZ + 4 * k);
    const float4 vv = *(const float4*)(vbase + nc * KSZ + 4 * k);
    float2 ndv[MM];
#pragma unroll
    for (int m = 0; m < MM; ++m)
      ndv[m] = *(const float2*)(nbase + ((size_t)m * NN + nc) * 8 + 2 * k);
#pragma unroll
    for (int m = 0; m < MM; ++m) {
      float p = kv.x * qr[m].x + kv.y * qr[m].y + kv.z * qr[m].z + kv.w * qr[m].w
              + ndv[m].x * qwr[m].x + ndv[m].y * qwr[m].y;
      p += __shfl_xor(p, 1); p += __shfl_xor(p, 2);
      const float e = ((pm >> m) & 1u) ? __expf(p) : 0.f;
      hacc[m].x = fmaf(e, vv.x, hacc[m].x);
      hacc[m].y = fmaf(e, vv.y, hacc[m].y);
      hacc[m].z = fmaf(e, vv.z, hacc[m].z);
      hacc[m].w = fmaf(e, vv.w, hacc[m].w);
      afv[m].x = fmaf(e, ndv[m].x, afv[m].x);
      afv[m].y = fmaf(e, ndv[m].y, afv[m].y);
      lsum += e;
    }
  }

  // reduce across the 16 groups of each wave (k-slot preserved by xor>=4)
#pragma unroll
  for (int m = 0; m < MM; ++m) {
#pragma unroll
    for (int off = 4; off <= 32; off <<= 1) {
      hacc[m].x += __shfl_xor(hacc[m].x, off);
      hacc[m].y += __shfl_xor(hacc[m].y, off);
      hacc[m].z += __shfl_xor(hacc[m].z, off);
      hacc[m].w += __shfl_xor(hacc[m].w, off);
      afv[m].x += __shfl_xor(afv[m].x, off);
      afv[m].y += __shfl_xor(afv[m].y, off);
    }
  }
#pragma unroll
  for (int off = 4; off <= 32; off <<= 1) lsum += __shfl_xor(lsum, off);

  __shared__ float redh[4][MM][KSZ];
  __shared__ float redaf[4][MM][8];
  __shared__ float reds[4];
  const int w = t >> 6;
  if ((t & 63) < 4) {
    const int kk = t & 3;
#pragma unroll
    for (int m = 0; m < MM; ++m) {
      redh[w][m][4 * kk + 0] = hacc[m].x;
      redh[w][m][4 * kk + 1] = hacc[m].y;
      redh[w][m][4 * kk + 2] = hacc[m].z;
      redh[w][m][4 * kk + 3] = hacc[m].w;
      redaf[w][m][2 * kk + 0] = afv[m].x;
      redaf[w][m][2 * kk + 1] = afv[m].y;
    }
  }
  if ((t & 63) == 0) reds[w] = lsum;
  __syncthreads();
  float* P = part + (size_t)blk * 128;
  if (t < 80) {
    const int m = t >> 4, kk = t & 15;
    P[t] = redh[0][m][kk] + redh[1][m][kk] + redh[2][m][kk] + redh[3][m][kk];
  } else if (t < 120) {
    const int r = t - 80, m = r >> 3, f = r & 7;
    P[80 + r] = redaf[0][m][f] + redaf[1][m][f] + redaf[2][m][f] + redaf[3][m][f];
  } else if (t == 120) {
    P[120] = reds[0] + reds[1] + reds[2] + reds[3];
  }
}

// ---------------- k2b: per-b combine (plain sums) -> conc -> fq, fw
__global__ __launch_bounds__(256) void k2b_combine(
    const float* __restrict__ part, const float* __restrict__ wpns,
    const float* __restrict__ po, float* __restrict__ fq_ws,
    float* __restrict__ fw_ws)
{
  const int b = blockIdx.x;
  const int t = threadIdx.x;
  __shared__ float pos[DD][129];   // stride 129: conflict-free column reads
  __shared__ float rgs[HH];
  __shared__ float afs[HH][MM][8];
  __shared__ float cs[MM][DD];
  __shared__ float fqs[MM][DD];

  for (int i = t; i < DD * DD / 4; i += 256) {
    const float4 v = ((const float4*)po)[i];
    const int r = (i * 4) >> 7, cc = (i * 4) & 127;
    pos[r][cc] = v.x; pos[r][cc + 1] = v.y; pos[r][cc + 2] = v.z; pos[r][cc + 3] = v.w;
  }
  const float* pb = part + (size_t)b * 32 * 128;   // 32 chunks: (h*4+c)
  if (t < HH) {
    float s = 0.f;
#pragma unroll
    for (int c = 0; c < NCH; ++c) s += pb[(t * 4 + c) * 128 + 120];
    rgs[t] = 1.f / s;
  }
  for (int idx = t; idx < HH * MM * 8; idx += 256) {
    const int h = idx / 40, r = idx % 40;
    float a = 0.f;
#pragma unroll
    for (int c = 0; c < NCH; ++c) a += pb[(h * 4 + c) * 128 + 80 + r];
    afs[h][r >> 3][r & 7] = a;
  }
  __syncthreads();
  for (int idx = t; idx < MM * DD; idx += 256) {
    const int m = idx >> 7, d = idx & 127, h = d >> 4;
    float a = 0.f;
#pragma unroll
    for (int c = 0; c < NCH; ++c) a += pb[(h * 4 + c) * 128 + m * 16 + (d & 15)];
    float cf = 0.f;
#pragma unroll
    for (int f = 0; f < 8; ++f) cf = fmaf(wpns[d * 8 + f], afs[h][m][f], cf);
    cs[m][d] = (a + cf) * rgs[h];
  }
  __syncthreads();
  for (int idx = t; idx < MM * DD; idx += 256) {
    const int m = idx >> 7, d = idx & 127;
    float acc = 0.f;
#pragma unroll 8
    for (int j = 0; j < DD; ++j) acc = fmaf(cs[m][j], pos[d][j], acc);
    acc *= INV_SQRT_D;   // fold 1/sqrt(D)
    fqs[m][d] = acc;
    fq_ws[(size_t)b * (MM * DD) + idx] = acc;
  }
  __syncthreads();
  if (t < MM * 8) {
    const int m = t >> 3, f = t & 7;
    float acc = 0.f;
#pragma unroll 16
    for (int d = 0; d < DD; ++d) acc = fmaf(fqs[m][d], wpns[(2 * DD + d) * 8 + f], acc);
    fw_ws[b * 40 + t] = acc;
  }
}

// ---------------- k3: per (b,chunk) logits via 16-lane shfl-dot, direct exp.
// b128 lK loads + packed mask. Writes e-values to out, per-chunk sum to stats.
__global__ __launch_bounds__(512) void k3_logits(
    const float* __restrict__ ndf, const float* __restrict__ lK,
    const unsigned int* __restrict__ pmask, const float* __restrict__ fq_ws,
    const float* __restrict__ fw_ws, float* __restrict__ out,
    float* __restrict__ stats)
{
  const int b = blockIdx.x >> 3;
  const int c = blockIdx.x & 7;
  const int t = threadIdx.x;
  const int k = t & 15, gid = t >> 4;   // 32 groups of 16 lanes
  const int n0 = c * CH3;

  float4 fqr[MM][2];
  float fwr[MM];
#pragma unroll
  for (int m = 0; m < MM; ++m) {
    fqr[m][0] = *(const float4*)(fq_ws + (size_t)(b * MM + m) * DD + 8 * k);
    fqr[m][1] = *(const float4*)(fq_ws + (size_t)(b * MM + m) * DD + 8 * k + 4);
    fwr[m] = fw_ws[b * 40 + m * 8 + (k & 7)];
  }
  float lsum = 0.f;

#pragma unroll
  for (int i = 0; i < 4; ++i) {
    const int nl = gid + 32 * i;
    const bool valid = (nl < CH3);          // group-uniform
    const int n = n0 + (valid ? nl : 0);
    const unsigned int pm = valid ? pmask[b * NN + n] : 0u;
    const float* lkr = lK + ((size_t)b * NN + n) * DD;
    const float4 l0 = *(const float4*)(lkr + 8 * k);
    const float4 l1 = *(const float4*)(lkr + 8 * k + 4);
    float ndv[MM];
#pragma unroll
    for (int m = 0; m < MM; ++m)
      ndv[m] = (k < 8) ? ndf[((size_t)(b * MM + m) * NN + n) * 8 + k] : 0.f;
#pragma unroll
    for (int m = 0; m < MM; ++m) {
      float p = l0.x * fqr[m][0].x + l0.y * fqr[m][0].y
              + l0.z * fqr[m][0].z + l0.w * fqr[m][0].w
              + l1.x * fqr[m][1].x + l1.y * fqr[m][1].y
              + l1.z * fqr[m][1].z + l1.w * fqr[m][1].w
              + ndv[m] * fwr[m];
      p += __shfl_xor(p, 1); p += __shfl_xor(p, 2);
      p += __shfl_xor(p, 4); p += __shfl_xor(p, 8);
      const float e = ((pm >> m) & 1u) ? __expf(tanh_fast(p) * 10.f) : 0.f;
      if (valid) {
        lsum += e;
        if (k == 0) out[(size_t)(b * MM + m) * NN + n] = e;
      }
    }
  }
  // per-lane lsum already holds its group's sum; xor16/32 sums the 4 groups.
  lsum += __shfl_xor(lsum, 16);
  lsum += __shfl_xor(lsum, 32);
  __shared__ float wred[8];
  if ((t & 63) == 0) wred[t >> 6] = lsum;
  __syncthreads();
  if (t == 0) {
    float s = 0.f;
#pragma unroll
    for (int w = 0; w < 8; ++w) s += wred[w];
    stats[b * NC3 + c] = s;
  }
}

// ---------------- k4: per (b,m) scale row by 1/sum
__global__ __launch_bounds__(256) void k4_probs(
    const float* __restrict__ stats, float* __restrict__ out)
{
  const int bm = blockIdx.x;
  const int b = bm / MM;
  const int t = threadIdx.x;
  float s = 0.f;
#pragma unroll
  for (int c = 0; c < NC3; ++c) s += stats[b * NC3 + c];
  const float scale = 1.f / s;
  if (t < 250) {
    float4* p = (float4*)(out + (size_t)bm * NN);
    float4 v = p[t];
    v.x *= scale; v.y *= scale; v.z *= scale; v.w *= scale;
    p[t] = v;
  }
}

extern "C" void kernel_launch(void* const* d_in, const int* in_sizes, int n_in,
                              void* d_out, int out_size, void* d_ws, size_t ws_size,
                              hipStream_t stream) {
  // d_in[0] = node_embeddings: dead input, never read.
  const float* fc   = (const float*)d_in[1];
  const float* pne  = (const float*)d_in[2];
  const float* ndf  = (const float*)d_in[3];
  const float* vdf  = (const float*)d_in[4];
  const float* gV   = (const float*)d_in[5];
  const float* gK   = (const float*)d_in[6];
  const float* lK   = (const float*)d_in[7];
  const int*   mask = (const int*)d_in[8];
  const float* wpcv = (const float*)d_in[9];
  const float* wpns = (const float*)d_in[10];
  const float* po   = (const float*)d_in[11];

  float* q_ws  = (float*)d_ws;                       // 40960
  float* qw_ws = q_ws + BB * MM * DD;                // 20480
  float* part  = qw_ws + BB * HH * MM * 8;           // 2048*128
  float* fq_ws = part + (size_t)BB * HH * NCH * 128; // 40960
  float* fw_ws = fq_ws + BB * MM * DD;               // 2560
  float* stats = fw_ws + BB * 40;                    // 512
  unsigned int* pmask = (unsigned int*)(stats + BB * NC3);  // 64000 u32
  float* out   = (float*)d_out;

  k1_query<<<BB * MM + BB, 256, 0, stream>>>(fc, pne, vdf, wpcv, wpns, mask,
                                             q_ws, qw_ws, pmask);
  k2_attn<<<BB * HH * NCH, 256, 0, stream>>>(ndf, gV, gK, pmask, q_ws, qw_ws, part);
  k2b_combine<<<BB, 256, 0, stream>>>(part, wpns, po, fq_ws, fw_ws);
  k3_logits<<<BB * NC3, 512, 0, stream>>>(ndf, lK, pmask, fq_ws, fw_ws, out, stats);
  k4_probs<<<BB * MM, 256, 0, stream>>>(stats, out);
}

// Round 6
// 56.989 us; speedup vs baseline: 2.4381x; 1.0326x over previous
//
#include <hip/hip_runtime.h>
#include <cstddef>

#define BB 64
#define MM 5
#define NN 1000
#define DD 128
#define HH 8
#define KSZ 16
#define NCH 4        // k2 attention chunks per (b,h)
#define CH2 250      // k2 chunk size
#define NC3 8        // k3 chunks per b
#define CH3 125      // k3 chunk size
#define INV_SQRT_D 0.08838834764831845f

__device__ __forceinline__ float tanh_fast(float x) {
  float e = __expf(2.f * x);
  return 1.f - 2.f / (e + 1.f);   // safe at +/-inf
}

// ---------------- k1: blocks [0,320): per-(b,m) query projection via 16-lane
// shfl-dot; blocks [320,384): pack feasibility mask bits -> pmask[b][n].
__global__ __launch_bounds__(256) void k1_query(
    const float* __restrict__ fc, const float* __restrict__ pne,
    const float* __restrict__ vdf, const float* __restrict__ wpcv,
    const float* __restrict__ wpns, const int* __restrict__ mask,
    float* __restrict__ q_ws, float* __restrict__ qw_ws,
    unsigned int* __restrict__ pmask)
{
  const int t = threadIdx.x;
  if (blockIdx.x >= BB * MM) {          // mask-pack blocks
    const int b = blockIdx.x - BB * MM;
    const int* mb = mask + (size_t)(b * MM) * NN;
    for (int n = t; n < NN; n += 256) {
      unsigned int pm = 0;
#pragma unroll
      for (int m = 0; m < MM; ++m) pm |= (mb[m * NN + n] != 0 ? 1u : 0u) << m;
      pmask[b * NN + n] = pm;
    }
    return;
  }
  const int bm = blockIdx.x;            // b*5 + m
  const int b = bm / MM;
  const int k = t & 15, gid = t >> 4;   // 16 groups of 16 lanes
  __shared__ float qsh[DD];

  float cvr[9];
  const float* pner = pne + (size_t)bm * DD;
#pragma unroll
  for (int jp = 0; jp < 8; ++jp) cvr[jp] = pner[k + 16 * jp];
  cvr[8] = (k < 3) ? vdf[bm * 3 + k] : 0.f;

#pragma unroll 2
  for (int dd = 0; dd < 8; ++dd) {
    const int d = gid + 16 * dd;
    const float* wrow = wpcv + d * 131;
    float p = 0.f;
#pragma unroll
    for (int jp = 0; jp < 8; ++jp) p = fmaf(cvr[jp], wrow[k + 16 * jp], p);
    if (k < 3) p = fmaf(cvr[8], wrow[128 + k], p);
    p += __shfl_xor(p, 1); p += __shfl_xor(p, 2);
    p += __shfl_xor(p, 4); p += __shfl_xor(p, 8);
    if (k == 0) {
      const float q = 0.25f * (p + fc[b * DD + d]);
      qsh[d] = q;
      q_ws[(size_t)bm * DD + d] = q;
    }
  }
  __syncthreads();
  if (t < 64) {
    const int h = t >> 3, f = t & 7;
    float acc = 0.f;
#pragma unroll
    for (int kk = 0; kk < KSZ; ++kk)
      acc = fmaf(qsh[h * KSZ + kk], wpns[(DD + h * KSZ + kk) * 8 + f], acc);
    qw_ws[(b * HH + h) * 40 + (bm % MM) * 8 + f] = acc;
  }
}

// ---------------- k2: per (b,h,chunk) single-pass attention partials.
// 4-lane groups; ALL 32 global loads hoisted up-front for max MLP.
// __launch_bounds__(256,3): allow ~170 VGPR so the hoist stays in registers.
__global__ __launch_bounds__(256, 3) void k2_attn(
    const float* __restrict__ ndf, const float* __restrict__ gV,
    const float* __restrict__ gK, const unsigned int* __restrict__ pmask,
    const float* __restrict__ q_ws, const float* __restrict__ qw_ws,
    float* __restrict__ part)
{
  const int blk = blockIdx.x;
  const int c = blk & 3;
  const int h = (blk >> 2) & 7;
  const int b = blk >> 5;
  const int t = threadIdx.x;
  const int k = t & 3, gid = t >> 2;    // 64 groups of 4 lanes
  const int n0 = c * CH2;

  const float* kbase = gK + ((size_t)(h * BB + b) * NN + n0) * KSZ;
  const float* vbase = gV + ((size_t)(h * BB + b) * NN + n0) * KSZ;
  const float* nbase = ndf + ((size_t)(b * MM) * NN + n0) * 8;
  const unsigned int* pmb = pmask + b * NN + n0;

  // ---- hoisted loads: 4 bodies x (K f4 + V f4 + 5x ndf f2 + pmask)
  float4 kv[4], vv[4];
  float2 ndv[4][MM];
  unsigned int pm[4];
#pragma unroll
  for (int i = 0; i < 4; ++i) {
    const int nl = gid + 64 * i;
    const bool valid = (nl < CH2);                 // group-uniform
    const int nc = valid ? nl : 0;
    pm[i] = valid ? pmb[nc] : 0u;
    kv[i] = *(const float4*)(kbase + nc * KSZ + 4 * k);
    vv[i] = *(const float4*)(vbase + nc * KSZ + 4 * k);
#pragma unroll
    for (int m = 0; m < MM; ++m)
      ndv[i][m] = *(const float2*)(nbase + ((size_t)m * NN + nc) * 8 + 2 * k);
  }

  float4 qr[MM];
  float2 qwr[MM];
#pragma unroll
  for (int m = 0; m < MM; ++m) {
    qr[m] = *(const float4*)(q_ws + (size_t)(b * MM + m) * DD + h * KSZ + 4 * k);
    qwr[m] = *(const float2*)(qw_ws + (b * HH + h) * 40 + m * 8 + 2 * k);
  }
  float4 hacc[MM] = {};
  float2 afv[MM] = {};
  float lsum = 0.f;

#pragma unroll
  for (int i = 0; i < 4; ++i) {
#pragma unroll
    for (int m = 0; m < MM; ++m) {
      float p = kv[i].x * qr[m].x + kv[i].y * qr[m].y
              + kv[i].z * qr[m].z + kv[i].w * qr[m].w
              + ndv[i][m].x * qwr[m].x + ndv[i][m].y * qwr[m].y;
      p += __shfl_xor(p, 1); p += __shfl_xor(p, 2);
      const float e = ((pm[i] >> m) & 1u) ? __expf(p) : 0.f;
      hacc[m].x = fmaf(e, vv[i].x, hacc[m].x);
      hacc[m].y = fmaf(e, vv[i].y, hacc[m].y);
      hacc[m].z = fmaf(e, vv[i].z, hacc[m].z);
      hacc[m].w = fmaf(e, vv[i].w, hacc[m].w);
      afv[m].x = fmaf(e, ndv[i][m].x, afv[m].x);
      afv[m].y = fmaf(e, ndv[i][m].y, afv[m].y);
      lsum += e;
    }
  }

  // reduce across the 16 groups of each wave (k-slot preserved by xor>=4)
#pragma unroll
  for (int m = 0; m < MM; ++m) {
#pragma unroll
    for (int off = 4; off <= 32; off <<= 1) {
      hacc[m].x += __shfl_xor(hacc[m].x, off);
      hacc[m].y += __shfl_xor(hacc[m].y, off);
      hacc[m].z += __shfl_xor(hacc[m].z, off);
      hacc[m].w += __shfl_xor(hacc[m].w, off);
      afv[m].x += __shfl_xor(afv[m].x, off);
      afv[m].y += __shfl_xor(afv[m].y, off);
    }
  }
#pragma unroll
  for (int off = 4; off <= 32; off <<= 1) lsum += __shfl_xor(lsum, off);

  __shared__ float redh[4][MM][KSZ];
  __shared__ float redaf[4][MM][8];
  __shared__ float reds[4];
  const int w = t >> 6;
  if ((t & 63) < 4) {
    const int kk = t & 3;
#pragma unroll
    for (int m = 0; m < MM; ++m) {
      redh[w][m][4 * kk + 0] = hacc[m].x;
      redh[w][m][4 * kk + 1] = hacc[m].y;
      redh[w][m][4 * kk + 2] = hacc[m].z;
      redh[w][m][4 * kk + 3] = hacc[m].w;
      redaf[w][m][2 * kk + 0] = afv[m].x;
      redaf[w][m][2 * kk + 1] = afv[m].y;
    }
  }
  if ((t & 63) == 0) reds[w] = lsum;
  __syncthreads();
  float* P = part + (size_t)blk * 128;
  if (t < 80) {
    const int m = t >> 4, kk = t & 15;
    P[t] = redh[0][m][kk] + redh[1][m][kk] + redh[2][m][kk] + redh[3][m][kk];
  } else if (t < 120) {
    const int r = t - 80, m = r >> 3, f = r & 7;
    P[80 + r] = redaf[0][m][f] + redaf[1][m][f] + redaf[2][m][f] + redaf[3][m][f];
  } else if (t == 120) {
    P[120] = reds[0] + reds[1] + reds[2] + reds[3];
  }
}

// ---------------- k3: per (b,chunk). Fused: combine partials -> conc -> fq,fw
// (k2b's job, redone per chunk-block; cheap) then streaming logits -> e-values.
__global__ __launch_bounds__(512) void k3_logits(
    const float* __restrict__ ndf, const float* __restrict__ lK,
    const unsigned int* __restrict__ pmask, const float* __restrict__ part,
    const float* __restrict__ wpns, const float* __restrict__ po,
    float* __restrict__ out, float* __restrict__ stats)
{
  const int b = blockIdx.x >> 3;
  const int c = blockIdx.x & 7;
  const int t = threadIdx.x;

  __shared__ float pos[DD][129];   // stride 129: conflict-free column reads
  __shared__ float rgs[HH];
  __shared__ float afs[HH][MM][8];
  __shared__ float cs[MM][DD];
  __shared__ float fqs[MM][DD];
  __shared__ float fw[MM][8];
  __shared__ float wred[8];

  // ---- stage po (coalesced) + per-h sums + AF combine
  for (int i = t; i < DD * DD / 4; i += 512) {
    const float4 v = ((const float4*)po)[i];
    const int r = (i * 4) >> 7, cc = (i * 4) & 127;
    pos[r][cc] = v.x; pos[r][cc + 1] = v.y; pos[r][cc + 2] = v.z; pos[r][cc + 3] = v.w;
  }
  const float* pb = part + (size_t)b * 32 * 128;   // 32 chunks: (h*4+cc)
  if (t < HH) {
    float s = 0.f;
#pragma unroll
    for (int cc = 0; cc < NCH; ++cc) s += pb[(t * 4 + cc) * 128 + 120];
    rgs[t] = 1.f / s;
  }
  if (t < HH * MM * 8) {
    const int h = t / 40, r = t % 40;
    float a = 0.f;
#pragma unroll
    for (int cc = 0; cc < NCH; ++cc) a += pb[(h * 4 + cc) * 128 + 80 + r];
    afs[h][r >> 3][r & 7] = a;
  }
  __syncthreads();
  // ---- conc
  for (int idx = t; idx < MM * DD; idx += 512) {
    const int m = idx >> 7, d = idx & 127, h = d >> 4;
    float a = 0.f;
#pragma unroll
    for (int cc = 0; cc < NCH; ++cc) a += pb[(h * 4 + cc) * 128 + m * 16 + (d & 15)];
    float cf = 0.f;
#pragma unroll
    for (int f = 0; f < 8; ++f) cf = fmaf(wpns[d * 8 + f], afs[h][m][f], cf);
    cs[m][d] = (a + cf) * rgs[h];
  }
  __syncthreads();
  // ---- fq = conc @ po.T (prescaled by 1/sqrt(D))
  for (int idx = t; idx < MM * DD; idx += 512) {
    const int m = idx >> 7, d = idx & 127;
    float acc = 0.f;
#pragma unroll 8
    for (int j = 0; j < DD; ++j) acc = fmaf(cs[m][j], pos[d][j], acc);
    fqs[m][d] = acc * INV_SQRT_D;
  }
  __syncthreads();
  // ---- fw
  if (t < MM * 8) {
    const int m = t >> 3, f = t & 7;
    float acc = 0.f;
#pragma unroll 16
    for (int d = 0; d < DD; ++d) acc = fmaf(fqs[m][d], wpns[(2 * DD + d) * 8 + f], acc);
    fw[m][f] = acc;
  }
  __syncthreads();

  // ---- streaming logits (16-lane shfl-dot, direct exp)
  const int k = t & 15, gid = t >> 4;   // 32 groups of 16 lanes
  const int n0 = c * CH3;
  float4 fqr[MM][2];
  float fwr[MM];
#pragma unroll
  for (int m = 0; m < MM; ++m) {
    fqr[m][0] = *(const float4*)(&fqs[m][8 * k]);
    fqr[m][1] = *(const float4*)(&fqs[m][8 * k + 4]);
    fwr[m] = fw[m][k & 7];
  }
  float lsum = 0.f;

#pragma unroll
  for (int i = 0; i < 4; ++i) {
    const int nl = gid + 32 * i;
    const bool valid = (nl < CH3);          // group-uniform
    const int n = n0 + (valid ? nl : 0);
    const unsigned int pm = valid ? pmask[b * NN + n] : 0u;
    const float* lkr = lK + ((size_t)b * NN + n) * DD;
    const float4 l0 = *(const float4*)(lkr + 8 * k);
    const float4 l1 = *(const float4*)(lkr + 8 * k + 4);
    float ndv[MM];
#pragma unroll
    for (int m = 0; m < MM; ++m)
      ndv[m] = (k < 8) ? ndf[((size_t)(b * MM + m) * NN + n) * 8 + k] : 0.f;
#pragma unroll
    for (int m = 0; m < MM; ++m) {
      float p = l0.x * fqr[m][0].x + l0.y * fqr[m][0].y
              + l0.z * fqr[m][0].z + l0.w * fqr[m][0].w
              + l1.x * fqr[m][1].x + l1.y * fqr[m][1].y
              + l1.z * fqr[m][1].z + l1.w * fqr[m][1].w
              + ndv[m] * fwr[m];
      p += __shfl_xor(p, 1); p += __shfl_xor(p, 2);
      p += __shfl_xor(p, 4); p += __shfl_xor(p, 8);
      const float e = ((pm >> m) & 1u) ? __expf(tanh_fast(p) * 10.f) : 0.f;
      if (valid) {
        lsum += e;
        if (k == 0) out[(size_t)(b * MM + m) * NN + n] = e;
      }
    }
  }
  // per-lane lsum already holds its group's sum; xor16/32 sums the 4 groups.
  lsum += __shfl_xor(lsum, 16);
  lsum += __shfl_xor(lsum, 32);
  if ((t & 63) == 0) wred[t >> 6] = lsum;
  __syncthreads();
  if (t == 0) {
    float s = 0.f;
#pragma unroll
    for (int w = 0; w < 8; ++w) s += wred[w];
    stats[b * NC3 + c] = s;
  }
}

// ---------------- k4: per (b,m) scale row by 1/sum
__global__ __launch_bounds__(256) void k4_probs(
    const float* __restrict__ stats, float* __restrict__ out)
{
  const int bm = blockIdx.x;
  const int b = bm / MM;
  const int t = threadIdx.x;
  float s = 0.f;
#pragma unroll
  for (int c = 0; c < NC3; ++c) s += stats[b * NC3 + c];
  const float scale = 1.f / s;
  if (t < 250) {
    float4* p = (float4*)(out + (size_t)bm * NN);
    float4 v = p[t];
    v.x *= scale; v.y *= scale; v.z *= scale; v.w *= scale;
    p[t] = v;
  }
}

extern "C" void kernel_launch(void* const* d_in, const int* in_sizes, int n_in,
                              void* d_out, int out_size, void* d_ws, size_t ws_size,
                              hipStream_t stream) {
  // d_in[0] = node_embeddings: dead input, never read.
  const float* fc   = (const float*)d_in[1];
  const float* pne  = (const float*)d_in[2];
  const float* ndf  = (const float*)d_in[3];
  const float* vdf  = (const float*)d_in[4];
  const float* gV   = (const float*)d_in[5];
  const float* gK   = (const float*)d_in[6];
  const float* lK   = (const float*)d_in[7];
  const int*   mask = (const int*)d_in[8];
  const float* wpcv = (const float*)d_in[9];
  const float* wpns = (const float*)d_in[10];
  const float* po   = (const float*)d_in[11];

  float* q_ws  = (float*)d_ws;                       // 40960
  float* qw_ws = q_ws + BB * MM * DD;                // 20480
  float* part  = qw_ws + BB * HH * MM * 8;           // 2048*128
  float* stats = part + (size_t)BB * HH * NCH * 128; // 512
  unsigned int* pmask = (unsigned int*)(stats + BB * NC3);  // 64000 u32
  float* out   = (float*)d_out;

  k1_query<<<BB * MM + BB, 256, 0, stream>>>(fc, pne, vdf, wpcv, wpns, mask,
                                             q_ws, qw_ws, pmask);
  k2_attn<<<BB * HH * NCH, 256, 0, stream>>>(ndf, gV, gK, pmask, q_ws, qw_ws, part);
  k3_logits<<<BB * NC3, 512, 0, stream>>>(ndf, lK, pmask, part, wpns, po, out, stats);
  k4_probs<<<BB * MM, 256, 0, stream>>>(stats, out);
}